// Round 6
// baseline (88.742 us; speedup 1.0000x reference)
//
#include <hip/hip_runtime.h>
#include <math.h>

#define N_ 2048
#define K_ 512
#define J_ 256
#define SPLIT 8
#define KR  (K_ / SPLIT)   // 64 k per block
#define KR4 (KR / 4)       // 16 float4 k-steps

typedef __attribute__((ext_vector_type(2))) float v2f;

// Block: 32n x 256j x 64k. 256 threads = 4 waves x (8 ln x 8 lj), thread-tile 4n x 8j.
// Both operands in LDS. Reads are exactly conflict-free:
//   x: addr (ln*4+i)*16 + ((k4+ln)&15)  -> 8 addrs, bank-group (k4+ln)&7 distinct, 8-lane bcast
//   w: addr jr*16 + ((k4+jr>>3)&15), jr>>3 = wave*8+lj -> 8 addrs/wave, (k4+lj)&7 distinct
// 12 b128 per 128 products = 1.5 B/product. 512 blocks -> 2/CU, 2 waves/SIMD, one barrier.
// Grid linearized id = split*64 + tile so split-siblings land on the same XCD (id%8 == tile%8).
__global__ __launch_bounds__(256, 2) void mam_partial(
    const float* __restrict__ x, const float* __restrict__ w,
    float* __restrict__ pmax, float* __restrict__ pmin)
{
    __shared__ __align__(16) float4 xs[32 * 16];    // 8 KB
    __shared__ __align__(16) float4 wsh[256 * 16];  // 64 KB

    const int t     = threadIdx.x;
    const int id    = blockIdx.x;
    const int tile  = id & 63;          // n-tile 0..63
    const int split = id >> 6;          // 0..7
    const int n0    = tile * 32;
    const int kc    = split * KR;

    const int lane = t & 63;
    const int wave = t >> 6;
    const int lj   = lane & 7;
    const int ln   = lane >> 3;
    const int jbase = wave * 64 + lj * 8;

    // ---- stage x: 32 rows x 16 float4 (2/thread) ----
#pragma unroll
    for (int r = 0; r < 2; ++r) {
        const int idx = r * 256 + t;
        const int row = idx >> 4;
        const int q   = idx & 15;
        const float4 g = *(const float4*)(x + (size_t)(n0 + row) * K_ + kc + q * 4);
        xs[row * 16 + ((q + (row >> 2)) & 15)] = g;
    }
    // ---- stage w: full 256 j-rows x 16 float4 (16/thread); shared by 64 sibling blocks -> L2 ----
#pragma unroll
    for (int r = 0; r < 16; ++r) {
        const int idx = r * 256 + t;
        const int jr  = idx >> 4;
        const int q   = idx & 15;
        const float4 g = *(const float4*)(w + (size_t)jr * K_ + kc + q * 4);
        wsh[jr * 16 + ((q + (jr >> 3)) & 15)] = g;
    }
    __syncthreads();   // the only barrier

    float mx[4][8], mn[4][8];
#pragma unroll
    for (int i = 0; i < 4; ++i)
#pragma unroll
        for (int j = 0; j < 8; ++j) { mx[i][j] = -__builtin_inff(); mn[i][j] = __builtin_inff(); }

    const int wrow = jbase >> 3;       // = wave*8 + lj, constant per thread
#pragma unroll 2
    for (int k4 = 0; k4 < KR4; ++k4) {
        float4 xv[4], wv[8];
#pragma unroll
        for (int i = 0; i < 4; ++i)
            xv[i] = xs[(ln * 4 + i) * 16 + ((k4 + ln) & 15)];
        const int cw = (k4 + wrow) & 15;
#pragma unroll
        for (int jj = 0; jj < 8; ++jj)
            wv[jj] = wsh[(jbase + jj) * 16 + cw];
#pragma unroll
        for (int i = 0; i < 4; ++i) {
            const v2f xa = {xv[i].x, xv[i].y};
            const v2f xb = {xv[i].z, xv[i].w};
#pragma unroll
            for (int jj = 0; jj < 8; ++jj) {
                const v2f wa = {wv[jj].x, wv[jj].y};
                const v2f wb = {wv[jj].z, wv[jj].w};
                const v2f pA = xa * wa;                         // v_pk_mul_f32
                const v2f pB = xb * wb;
                mx[i][jj] = fmaxf(fmaxf(mx[i][jj], pA.x), pA.y);  // v_max3_f32
                mn[i][jj] = fminf(fminf(mn[i][jj], pA.x), pA.y);
                mx[i][jj] = fmaxf(fmaxf(mx[i][jj], pB.x), pB.y);
                mn[i][jj] = fminf(fminf(mn[i][jj], pB.x), pB.y);
            }
        }
    }

    // ---- store partials [split][n][j] (writes stay in this XCD's L2) ----
#pragma unroll
    for (int i = 0; i < 4; ++i) {
        const size_t off = ((size_t)split * N_ + n0 + ln * 4 + i) * J_ + jbase;
        *(float4*)(pmax + off)     = make_float4(mx[i][0], mx[i][1], mx[i][2], mx[i][3]);
        *(float4*)(pmax + off + 4) = make_float4(mx[i][4], mx[i][5], mx[i][6], mx[i][7]);
        *(float4*)(pmin + off)     = make_float4(mn[i][0], mn[i][1], mn[i][2], mn[i][3]);
        *(float4*)(pmin + off + 4) = make_float4(mn[i][4], mn[i][5], mn[i][6], mn[i][7]);
    }
}

// Fold 8 K-splits + bias. Block b handles tile b&63 (same id%8 as the partial blocks that
// wrote it -> same XCD -> L2-hit reads). 512 blocks x 256 thr, one float4/thread.
__global__ __launch_bounds__(256) void mam_combine(
    const float* __restrict__ pmax, const float* __restrict__ pmin,
    const float* __restrict__ bias, float* __restrict__ out)
{
    const int b    = blockIdx.x;
    const int tile = b & 63;
    const int sub  = b >> 6;                       // 0..7
    const int tid  = threadIdx.x;
    const int r    = tid >> 6;                     // 0..3
    const int col4 = tid & 63;                     // float4 col
    const int n    = tile * 32 + sub * 4 + r;
    const int f    = n * (J_ / 4) + col4;
    const int PLANE4 = N_ * J_ / 4;

    const float4* pm = (const float4*)pmax;
    const float4* pn = (const float4*)pmin;
    float4 a = pm[f];
    float4 c = pn[f];
#pragma unroll
    for (int s = 1; s < SPLIT; ++s) {
        const float4 a2 = pm[(size_t)s * PLANE4 + f];
        const float4 c2 = pn[(size_t)s * PLANE4 + f];
        a.x = fmaxf(a.x, a2.x); a.y = fmaxf(a.y, a2.y);
        a.z = fmaxf(a.z, a2.z); a.w = fmaxf(a.w, a2.w);
        c.x = fminf(c.x, c2.x); c.y = fminf(c.y, c2.y);
        c.z = fminf(c.z, c2.z); c.w = fminf(c.w, c2.w);
    }
    const float4 bi = ((const float4*)bias)[col4];
    float4 o;
    o.x = a.x + c.x + bi.x;
    o.y = a.y + c.y + bi.y;
    o.z = a.z + c.z + bi.z;
    o.w = a.w + c.w + bi.w;
    ((float4*)out)[f] = o;
}

// Fallback if ws is too small (not expected; ws ~256 MB per profile).
__global__ __launch_bounds__(256) void mam_naive(
    const float* __restrict__ x, const float* __restrict__ w,
    const float* __restrict__ bias, float* __restrict__ out)
{
    const int n = blockIdx.x;
    const int j = threadIdx.x;
    float mx = -__builtin_inff(), mn = __builtin_inff();
    for (int k = 0; k < K_; ++k) {
        const float p = x[(size_t)n * K_ + k] * w[(size_t)j * K_ + k];
        mx = fmaxf(mx, p);
        mn = fminf(mn, p);
    }
    out[(size_t)n * J_ + j] = mx + mn + bias[j];
}

extern "C" void kernel_launch(void* const* d_in, const int* in_sizes, int n_in,
                              void* d_out, int out_size, void* d_ws, size_t ws_size,
                              hipStream_t stream) {
    const float* x    = (const float*)d_in[0];
    const float* w    = (const float*)d_in[1];
    const float* bias = (const float*)d_in[2];
    float* out = (float*)d_out;

    const size_t need = (size_t)SPLIT * 2 * N_ * J_ * sizeof(float);  // 32 MB
    if (ws_size >= need) {
        float* pmax = (float*)d_ws;
        float* pmin = pmax + (size_t)SPLIT * N_ * J_;
        mam_partial<<<dim3(64 * SPLIT), 256, 0, stream>>>(x, w, pmax, pmin);
        mam_combine<<<dim3(512), 256, 0, stream>>>(pmax, pmin, bias, out);
    } else {
        mam_naive<<<N_, 256, 0, stream>>>(x, w, bias, out);
    }
}